// Round 4
// baseline (404.978 us; speedup 1.0000x reference)
//
#include <hip/hip_runtime.h>

typedef unsigned short u16;
typedef unsigned int   u32;
typedef __attribute__((ext_vector_type(8))) short short8;   // 8 bf16 (4 VGPRs)
typedef __attribute__((ext_vector_type(4))) float floatx4;  // MFMA acc

#define T_DIM 4096
#define D_DIM 2048
#define H_DIM 256
#define M_DIM 16384   // B*T
#define NFLAT 8192    // D*W

__device__ __forceinline__ u16 f2bf(float f) {
  union { float f; u32 u; } c; c.f = f;
  u32 x = c.u;
  x += 0x7FFFu + ((x >> 16) & 1u);   // RNE
  return (u16)(x >> 16);
}
__device__ __forceinline__ u32 pk2(float a, float b) {
  return (u32)f2bf(a) | ((u32)f2bf(b) << 16);
}

// async global->LDS, 16B per lane. LDS dest = wave-uniform base + lane*16.
__device__ __forceinline__ void glds16(const void* g, void* l) {
  __builtin_amdgcn_global_load_lds(
      (const __attribute__((address_space(1))) void*)g,
      (__attribute__((address_space(3))) void*)l, 16, 0, 0);
}

// ------------- fused transpose+cvt for BOTH weights (one launch) ------------
__global__ void __launch_bounds__(256) tr_cvt_all(const float* __restrict__ w1,
                                                  u16* __restrict__ w1t,
                                                  const float* __restrict__ w2,
                                                  u16* __restrict__ w2t) {
  __shared__ u16 tile[32][33];
  int bid = blockIdx.x;
  const float* src; u16* dst; int R, C, c0, r0;
  if (bid < 512) {                       // w1 [2048][256] -> w1t [256][2048]
    src = w1; dst = w1t; R = D_DIM; C = H_DIM;
    c0 = (bid & 7) * 32; r0 = (bid >> 3) * 32;
  } else {                               // w2 [256][8192] -> w2t [8192][256]
    int b = bid - 512;
    src = w2; dst = w2t; R = H_DIM; C = NFLAT;
    c0 = (b & 255) * 32; r0 = (b >> 8) * 32;
  }
  const int tx = threadIdx.x & 31;
  const int ty = threadIdx.x >> 5;       // 0..7
  #pragma unroll
  for (int i = ty; i < 32; i += 8)
    tile[i][tx] = f2bf(src[(size_t)(r0 + i) * C + (c0 + tx)]);
  __syncthreads();
  #pragma unroll
  for (int i = ty; i < 32; i += 8)
    dst[(size_t)(c0 + i) * R + (r0 + tx)] = tile[tx][i];
}

// ---------------- GEMM1: h = silu(x @ w1), fp32 x inline-cvt ----------------
// tile 64(M) x 128(N), BK=64 -> 32 k-iters. grid = (2, 256) = 512 blocks.
// 2-phase pipeline: stage tile t+1 (glds B + reg->LDS A) while computing t;
// ONE vmcnt-drain barrier per iter. As/Bs double-buffered. 48 KB -> 3 blk/CU.
__global__ void __launch_bounds__(256) gemm1_silu(const float* __restrict__ X,   // [M][2048]
                                                  const u16* __restrict__ Bt,    // w1t [256][2048]
                                                  u16* __restrict__ H) {         // [M][256]
  __shared__ __align__(16) u16 As[2][64][64];    // 16 KB
  __shared__ __align__(16) u16 Bs[2][128][64];   // 32 KB
  const int tid  = threadIdx.x;
  const int lane = tid & 63, l15 = lane & 15, quad = lane >> 4;
  const int wv   = tid >> 6, wy = wv >> 1, wx = wv & 1;
  const int m0   = blockIdx.y * 64;
  const int n0   = blockIdx.x * 128;
  const int srow = lane >> 3, sc = lane & 7;     // glds chunk coords

  floatx4 acc[2][4];
  const floatx4 zf = {0.f, 0.f, 0.f, 0.f};
  #pragma unroll
  for (int i = 0; i < 2; ++i)
    #pragma unroll
    for (int j = 0; j < 4; ++j) acc[i][j] = zf;

  float4 fA[2][2];                               // A fp32 reg prefetch (one tile)

#define G1_LOADA(KT)                                                          \
  _Pragma("unroll")                                                           \
  for (int i = 0; i < 2; ++i) {                                               \
    int s = i * 256 + tid, row = s >> 3, g = s & 7;                           \
    const float* xs = &X[(size_t)(m0 + row) * D_DIM + (KT) * 64 + g * 8];     \
    fA[i][0] = *(const float4*)xs;                                            \
    fA[i][1] = *(const float4*)(xs + 4);                                      \
  }

#define G1_WRITEA(BUF)                                                        \
  _Pragma("unroll")                                                           \
  for (int i = 0; i < 2; ++i) {                                               \
    int s = i * 256 + tid, row = s >> 3, g = s & 7, c = g ^ (row & 7);        \
    uint4 pk;                                                                 \
    pk.x = pk2(fA[i][0].x, fA[i][0].y);                                       \
    pk.y = pk2(fA[i][0].z, fA[i][0].w);                                       \
    pk.z = pk2(fA[i][1].x, fA[i][1].y);                                       \
    pk.w = pk2(fA[i][1].z, fA[i][1].w);                                       \
    *(uint4*)&As[BUF][row][c * 8] = pk;                                       \
  }

#define G1_STAGEB(KT, BUF)                                                    \
  _Pragma("unroll")                                                           \
  for (int ci = 0; ci < 4; ++ci) {                                            \
    int ch  = ci * 4 + wv;                                                    \
    int row = ch * 8 + srow;                                                  \
    glds16(&Bt[(size_t)(n0 + row) * D_DIM + (KT) * 64 + (sc ^ (row & 7)) * 8],\
           (char*)Bs + (BUF) * 16384 + ch * 1024);                            \
  }

  // prologue: tile 0 resident, fA holds tile 1
  G1_LOADA(0);
  G1_STAGEB(0, 0);
  G1_WRITEA(0);          // waits fA(0)
  G1_LOADA(1);
  __syncthreads();       // drain glds(0) + fA(1)

  #pragma unroll 2
  for (int t = 0; t < 32; ++t) {
    const int b = t & 1;
    if (t + 1 < 32) {
      G1_WRITEA(b ^ 1);          // tile t+1 from fA (loaded iter t-1: no stall)
      G1_STAGEB(t + 1, b ^ 1);
    }
    if (t + 2 < 32) G1_LOADA(t + 2);
    short8 af[2][2], bfr[4][2];
    #pragma unroll
    for (int ks = 0; ks < 2; ++ks) {
      #pragma unroll
      for (int mi = 0; mi < 2; ++mi) {
        int row = wy * 32 + mi * 16 + l15;
        af[mi][ks] = *(const short8*)&As[b][row][((ks * 4 + quad) ^ (row & 7)) * 8];
      }
      #pragma unroll
      for (int ni = 0; ni < 4; ++ni) {
        int row = wx * 64 + ni * 16 + l15;
        bfr[ni][ks] = *(const short8*)&Bs[b][row][((ks * 4 + quad) ^ (row & 7)) * 8];
      }
    }
    #pragma unroll
    for (int ks = 0; ks < 2; ++ks)
      #pragma unroll
      for (int mi = 0; mi < 2; ++mi)
        #pragma unroll
        for (int ni = 0; ni < 4; ++ni)
          acc[mi][ni] = __builtin_amdgcn_mfma_f32_16x16x32_bf16(af[mi][ks], bfr[ni][ks], acc[mi][ni], 0, 0, 0);
    if (t + 1 < 32) __syncthreads();   // ONE drain/barrier per iter; none after last
  }

  #pragma unroll
  for (int mi = 0; mi < 2; ++mi)
    #pragma unroll
    for (int ni = 0; ni < 4; ++ni)
      #pragma unroll
      for (int r = 0; r < 4; ++r) {
        float v = acc[mi][ni][r];
        v = v / (1.f + __expf(-v));
        int row = m0 + wy * 32 + mi * 16 + quad * 4 + r;
        int col = n0 + wx * 64 + ni * 16 + l15;
        H[(size_t)row * H_DIM + col] = f2bf(v);
      }
#undef G1_LOADA
#undef G1_WRITEA
#undef G1_STAGEB
}

// ---- GEMM2 fused: flat = h @ w2 + b2 ; out = silu(conv(flat, x)) ----------
// tile 128 tokens x 64 flat cols (=16 d-channels). K=256 fully resident:
//   - A (Hin) is WAVE-PRIVATE (waves stacked in M, 32 tokens each) -> loaded
//     straight to registers, full K: af[2][8] = 64 VGPR. No LDS, no barrier.
//   - B (w2t, shared) staged ONCE into 32 KB LDS via glds, XOR-swizzled.
//   => exactly ONE __syncthreads per block; K-loop is pure ds_read+MFMA.
// B rows permuted at stage time so flat col = d*4 + ni -> register conv
// epilogue (lane channel d = d0 + l15, tap = ni).
__global__ void __launch_bounds__(256) gemm2_conv_silu(const u16* __restrict__ Hin,   // [M][256] bf16
                                                       const u16* __restrict__ Bt,    // w2t [8192][256] bf16
                                                       const float* __restrict__ bias,// [8192] fp32
                                                       const float* __restrict__ X,   // [M][2048] fp32
                                                       float* __restrict__ Out) {     // [M][2048] fp32
  __shared__ __align__(16) u16 Bs[64][256];      // 32 KB, row stride 512 B
  const int tid  = threadIdx.x;
  const int lane = tid & 63, l15 = lane & 15, quad = lane >> 4;
  const int wv   = tid >> 6;                     // wave owns tokens wv*32..+31
  const int m0   = blockIdx.y * 128;
  const int d0   = blockIdx.x * 16;

  // ---- stage Bs once: 32 chunks of 1 KB (2 rows each), 8 per wave ---------
  #pragma unroll
  for (int i = 0; i < 8; ++i) {
    int ch  = wv * 8 + i;
    int row = ch * 2 + (lane >> 5);              // 0..63
    int s   = lane & 31;                         // 16B slot within row
    int g   = s ^ (row & 7);                     // swizzled k-chunk source
    int fc  = (d0 + (row & 15)) * 4 + (row >> 4);
    glds16(&Bt[(size_t)fc * H_DIM + g * 8], (char*)Bs + ch * 1024);
  }

  // ---- A panel straight to registers, full K (wave-private rows) ----------
  short8 af[2][8];
  #pragma unroll
  for (int mi = 0; mi < 2; ++mi) {
    const u16* arow = &Hin[(size_t)(m0 + wv * 32 + mi * 16 + l15) * H_DIM + quad * 8];
    #pragma unroll
    for (int ks = 0; ks < 8; ++ks)
      af[mi][ks] = *(const short8*)(arow + ks * 32);
  }

  __syncthreads();                               // the ONLY barrier: Bs ready

  floatx4 acc[2][4];
  const floatx4 zf = {0.f, 0.f, 0.f, 0.f};
  #pragma unroll
  for (int i = 0; i < 2; ++i)
    #pragma unroll
    for (int j = 0; j < 4; ++j) acc[i][j] = zf;

  #pragma unroll
  for (int ks = 0; ks < 8; ++ks) {               // pure ds_read + MFMA, no sync
    short8 bfr[4];
    #pragma unroll
    for (int ni = 0; ni < 4; ++ni) {
      int rb = ni * 16 + l15;
      int c  = (ks * 4 + quad) ^ (rb & 7);
      bfr[ni] = *(const short8*)((const char*)Bs + rb * 512 + c * 16);
    }
    #pragma unroll
    for (int mi = 0; mi < 2; ++mi)
      #pragma unroll
      for (int ni = 0; ni < 4; ++ni)
        acc[mi][ni] = __builtin_amdgcn_mfma_f32_16x16x32_bf16(af[mi][ks], bfr[ni], acc[mi][ni], 0, 0, 0);
  }

  // -------- register epilogue: bias + causal conv + silu, no LDS -----------
  const int d     = d0 + l15;                      // this lane's channel
  const float4 bv = *(const float4*)&bias[(size_t)d * 4];  // taps w=0..3
  const int tbase = m0 & (T_DIM - 1);              // tiles never straddle batch
  const int bbase = m0 - tbase;
  const float* xcol = &X[(size_t)bbase * D_DIM + d];
  float* ocol       = &Out[(size_t)m0 * D_DIM + d];

  #pragma unroll
  for (int mi = 0; mi < 2; ++mi) {
    int t0 = wv * 32 + mi * 16 + quad * 4;         // local token of r=0
    int tq = tbase + t0;                           // token within batch
    float xv[7];                                   // x[tq-3 .. tq+3] for this d
    #pragma unroll
    for (int j = 0; j < 7; ++j) {
      int tt = tq - 3 + j;
      xv[j] = (tt >= 0) ? xcol[(size_t)tt * D_DIM] : 0.f;
    }
    #pragma unroll
    for (int r = 0; r < 4; ++r) {
      float c0 = acc[mi][0][r] + bv.x;
      float c1 = acc[mi][1][r] + bv.y;
      float c2 = acc[mi][2][r] + bv.z;
      float c3 = acc[mi][3][r] + bv.w;
      float o  = c0 * xv[r] + c1 * xv[r + 1] + c2 * xv[r + 2] + c3 * xv[r + 3];
      float y  = o / (1.f + __expf(-o));
      ocol[(size_t)(t0 + r) * D_DIM] = y;
    }
  }
}

extern "C" void kernel_launch(void* const* d_in, const int* in_sizes, int n_in,
                              void* d_out, int out_size, void* d_ws, size_t ws_size,
                              hipStream_t stream) {
  const float* x  = (const float*)d_in[0];   // [4,4096,2048]
  const float* w1 = (const float*)d_in[1];   // [2048,256]
  const float* w2 = (const float*)d_in[2];   // [256,8192]
  const float* b2 = (const float*)d_in[3];   // [8192]
  float* out = (float*)d_out;                // [4,4096,2048]

  // ws layout (u16 elems): w1t 512K | w2t 2M | h 4M  (= ~13.6 MB)
  u16* w1t = (u16*)d_ws;                     // [256][2048]
  u16* w2t = w1t + (size_t)H_DIM * D_DIM;    // [8192][256]
  u16* h   = w2t + (size_t)NFLAT * H_DIM;    // [16384][256]

  tr_cvt_all<<<512 + 2048, 256, 0, stream>>>(w1, w1t, w2, w2t);
  gemm1_silu<<<dim3(2, M_DIM / 64), 256, 0, stream>>>(x, w1t, h);
  gemm2_conv_silu<<<dim3(D_DIM / 16, M_DIM / 128), 256, 0, stream>>>(h, w2t, b2, x, out);
}

// Round 5
// 380.771 us; speedup vs baseline: 1.0636x; 1.0636x over previous
//
#include <hip/hip_runtime.h>

typedef unsigned short u16;
typedef unsigned int   u32;
typedef __attribute__((ext_vector_type(8))) short short8;   // 8 bf16 (4 VGPRs)
typedef __attribute__((ext_vector_type(4))) float floatx4;  // MFMA acc

#define T_DIM 4096
#define D_DIM 2048
#define H_DIM 256
#define M_DIM 16384   // B*T
#define NFLAT 8192    // D*W

__device__ __forceinline__ u16 f2bf(float f) {
  union { float f; u32 u; } c; c.f = f;
  u32 x = c.u;
  x += 0x7FFFu + ((x >> 16) & 1u);   // RNE
  return (u16)(x >> 16);
}
__device__ __forceinline__ u32 pk2(float a, float b) {
  return (u32)f2bf(a) | ((u32)f2bf(b) << 16);
}

// async global->LDS, 16B per lane. LDS dest = wave-uniform base + lane*16.
__device__ __forceinline__ void glds16(const void* g, void* l) {
  __builtin_amdgcn_global_load_lds(
      (const __attribute__((address_space(1))) void*)g,
      (__attribute__((address_space(3))) void*)l, 16, 0, 0);
}

// ------------- fused transpose+cvt for BOTH weights (one launch) ------------
__global__ void __launch_bounds__(256) tr_cvt_all(const float* __restrict__ w1,
                                                  u16* __restrict__ w1t,
                                                  const float* __restrict__ w2,
                                                  u16* __restrict__ w2t) {
  __shared__ u16 tile[32][33];
  int bid = blockIdx.x;
  const float* src; u16* dst; int R, C, c0, r0;
  if (bid < 512) {                       // w1 [2048][256] -> w1t [256][2048]
    src = w1; dst = w1t; R = D_DIM; C = H_DIM;
    c0 = (bid & 7) * 32; r0 = (bid >> 3) * 32;
  } else {                               // w2 [256][8192] -> w2t [8192][256]
    int b = bid - 512;
    src = w2; dst = w2t; R = H_DIM; C = NFLAT;
    c0 = (b & 255) * 32; r0 = (b >> 8) * 32;
  }
  const int tx = threadIdx.x & 31;
  const int ty = threadIdx.x >> 5;       // 0..7
  #pragma unroll
  for (int i = ty; i < 32; i += 8)
    tile[i][tx] = f2bf(src[(size_t)(r0 + i) * C + (c0 + tx)]);
  __syncthreads();
  #pragma unroll
  for (int i = ty; i < 32; i += 8)
    dst[(size_t)(c0 + i) * R + (r0 + tx)] = tile[tx][i];
}

// ---------------- GEMM1: h = silu(x @ w1), fp32 x inline-cvt ----------------
// tile 64(M) x 64(N), BK=64 -> 32 k-iters. grid = (4, 256) = 1024 blocks
// = 4 blocks/CU (R1-R4's 512 blocks = 2/CU starved the 32-barrier loop).
// 2-phase dbuf (verified machinery); LDS 32 KB. Waves 2x2, wave tile 32x32.
// XCD swizzle: each XCD owns a contiguous m-range (streams a disjoint X slice).
__global__ void __launch_bounds__(256) gemm1_silu(const float* __restrict__ X,   // [M][2048]
                                                  const u16* __restrict__ Bt,    // w1t [256][2048]
                                                  u16* __restrict__ H) {         // [M][256]
  __shared__ __align__(16) u16 As[2][64][64];    // 16 KB
  __shared__ __align__(16) u16 Bs[2][64][64];    // 16 KB
  const int tid  = threadIdx.x;
  const int lane = tid & 63, l15 = lane & 15, quad = lane >> 4;
  const int wv   = tid >> 6, wy = wv >> 1, wx = wv & 1;
  // bijective XCD swizzle (nwg=1024, nwg%8==0): XCD k -> m-tiles [32k,32k+32)
  const int lin  = blockIdx.x + blockIdx.y * 4;
  const int wgid = (lin & 7) * 128 + (lin >> 3);
  const int m0   = (wgid >> 2) * 64;
  const int n0   = (wgid & 3) * 64;
  const int srow = lane >> 3, sc = lane & 7;     // glds chunk coords

  floatx4 acc[2][2];
  const floatx4 zf = {0.f, 0.f, 0.f, 0.f};
  #pragma unroll
  for (int i = 0; i < 2; ++i)
    #pragma unroll
    for (int j = 0; j < 2; ++j) acc[i][j] = zf;

  float4 fA[2][2];                               // A fp32 reg prefetch (one tile)

#define G1_LOADA(KT)                                                          \
  _Pragma("unroll")                                                           \
  for (int i = 0; i < 2; ++i) {                                               \
    int s = i * 256 + tid, row = s >> 3, g = s & 7;                           \
    const float* xs = &X[(size_t)(m0 + row) * D_DIM + (KT) * 64 + g * 8];     \
    fA[i][0] = *(const float4*)xs;                                            \
    fA[i][1] = *(const float4*)(xs + 4);                                      \
  }

#define G1_WRITEA(BUF)                                                        \
  _Pragma("unroll")                                                           \
  for (int i = 0; i < 2; ++i) {                                               \
    int s = i * 256 + tid, row = s >> 3, g = s & 7, c = g ^ (row & 7);        \
    uint4 pk;                                                                 \
    pk.x = pk2(fA[i][0].x, fA[i][0].y);                                       \
    pk.y = pk2(fA[i][0].z, fA[i][0].w);                                       \
    pk.z = pk2(fA[i][1].x, fA[i][1].y);                                       \
    pk.w = pk2(fA[i][1].z, fA[i][1].w);                                       \
    *(uint4*)&As[BUF][row][c * 8] = pk;                                       \
  }

#define G1_STAGEB(KT, BUF)                                                    \
  _Pragma("unroll")                                                           \
  for (int ci = 0; ci < 2; ++ci) {               /* 8 chunks, 2 per wave */   \
    int ch  = wv * 2 + ci;                                                    \
    int row = ch * 8 + srow;                                                  \
    glds16(&Bt[(size_t)(n0 + row) * D_DIM + (KT) * 64 + (sc ^ (row & 7)) * 8],\
           (char*)Bs + (BUF) * 8192 + ch * 1024);                             \
  }

  // prologue: tile 0 resident, fA holds tile 1
  G1_LOADA(0);
  G1_STAGEB(0, 0);
  G1_WRITEA(0);          // waits fA(0)
  G1_LOADA(1);
  __syncthreads();       // drain glds(0) + fA(1)

  #pragma unroll 2
  for (int t = 0; t < 32; ++t) {
    const int b = t & 1;
    if (t + 1 < 32) {
      G1_WRITEA(b ^ 1);          // tile t+1 from fA (loaded iter t-1: no stall)
      G1_STAGEB(t + 1, b ^ 1);
    }
    if (t + 2 < 32) G1_LOADA(t + 2);
    short8 af[2][2], bfr[2][2];
    #pragma unroll
    for (int ks = 0; ks < 2; ++ks) {
      #pragma unroll
      for (int mi = 0; mi < 2; ++mi) {
        int row = wy * 32 + mi * 16 + l15;
        af[mi][ks] = *(const short8*)&As[b][row][((ks * 4 + quad) ^ (row & 7)) * 8];
      }
      #pragma unroll
      for (int ni = 0; ni < 2; ++ni) {
        int row = wx * 32 + ni * 16 + l15;
        bfr[ni][ks] = *(const short8*)&Bs[b][row][((ks * 4 + quad) ^ (row & 7)) * 8];
      }
    }
    #pragma unroll
    for (int ks = 0; ks < 2; ++ks)
      #pragma unroll
      for (int mi = 0; mi < 2; ++mi)
        #pragma unroll
        for (int ni = 0; ni < 2; ++ni)
          acc[mi][ni] = __builtin_amdgcn_mfma_f32_16x16x32_bf16(af[mi][ks], bfr[ni][ks], acc[mi][ni], 0, 0, 0);
    if (t + 1 < 32) __syncthreads();   // ONE drain/barrier per iter; none after last
  }

  #pragma unroll
  for (int mi = 0; mi < 2; ++mi)
    #pragma unroll
    for (int ni = 0; ni < 2; ++ni)
      #pragma unroll
      for (int r = 0; r < 4; ++r) {
        float v = acc[mi][ni][r];
        v = v / (1.f + __expf(-v));
        int row = m0 + wy * 32 + mi * 16 + quad * 4 + r;
        int col = n0 + wx * 32 + ni * 16 + l15;
        H[(size_t)row * H_DIM + col] = f2bf(v);
      }
#undef G1_LOADA
#undef G1_WRITEA
#undef G1_STAGEB
}

// ---- GEMM2 fused: flat = h @ w2 + b2 ; out = silu(conv(flat, x)) ----------
// EXACT revert to the Round-1 kernel (measured 100 us; every restructure
// since regressed): tile 128 tokens x 128 flat cols, BK=64, 4 iters,
// single-buffer 32 KB, {sync; stage; sync; compute} per iter, permuted-B
// register conv epilogue. ONLY addition: bijective XCD swizzle so each XCD
// owns a contiguous m-range (Hin slice 1 MB + w2t 4 MB -> XCD-L2-resident;
// R4 showed 8x redundant Hin HBM fetch from round-robin dispatch).
__global__ void __launch_bounds__(256) gemm2_conv_silu(const u16* __restrict__ Hin,   // [M][256] bf16
                                                       const u16* __restrict__ Bt,    // w2t [8192][256] bf16
                                                       const float* __restrict__ bias,// [8192] fp32
                                                       const float* __restrict__ X,   // [M][2048] fp32
                                                       float* __restrict__ Out) {     // [M][2048] fp32
  __shared__ __align__(16) u16 As[128][64];   // 16 KB
  __shared__ __align__(16) u16 Bs[128][64];   // 16 KB
  const int tid  = threadIdx.x;
  const int lane = tid & 63, l15 = lane & 15, quad = lane >> 4;
  const int wv   = tid >> 6, wy = wv >> 1, wx = wv & 1;
  // bijective XCD swizzle (nwg=8192, nwg%8==0): XCD k -> m-tiles [16k,16k+16)
  const int lin  = blockIdx.x + blockIdx.y * 64;
  const int wgid = (lin & 7) * 1024 + (lin >> 3);
  const int m0   = (wgid >> 6) * 128;
  const int d0   = (wgid & 63) * 32;
  const int srow = lane >> 3, sc = lane & 7;

  floatx4 acc[4][4];
  const floatx4 zf = {0.f, 0.f, 0.f, 0.f};
  #pragma unroll
  for (int i = 0; i < 4; ++i)
    #pragma unroll
    for (int j = 0; j < 4; ++j) acc[i][j] = zf;

  for (int k0 = 0; k0 < H_DIM; k0 += 64) {    // 4 iterations
    __syncthreads();
    #pragma unroll
    for (int ci = 0; ci < 4; ++ci) {
      int ch  = ci * 4 + wv;                  // 16 chunks of 1 KB each
      int row = ch * 8 + srow;                // 0..127
      int g   = (sc ^ (row & 7)) * 8;         // swizzled k-chunk source
      glds16(&Hin[(size_t)(m0 + row) * H_DIM + k0 + g], (char*)As + ch * 1024);
      // permuted w2t row: Bs row (wx*64+ni*16+l15) <-> flat col (d0+wx*16+l15)*4+ni
      int fc = (d0 + ((row >> 6) << 4) + (row & 15)) * 4 + ((row >> 4) & 3);
      glds16(&Bt[(size_t)fc * H_DIM + k0 + g], (char*)Bs + ch * 1024);
    }
    __syncthreads();
    short8 af[4][2], bfr[4][2];
    #pragma unroll
    for (int ks = 0; ks < 2; ++ks) {
      #pragma unroll
      for (int mi = 0; mi < 4; ++mi) {
        int row = wy * 64 + mi * 16 + l15;
        af[mi][ks] = *(const short8*)&As[row][((ks * 4 + quad) ^ (row & 7)) * 8];
      }
      #pragma unroll
      for (int ni = 0; ni < 4; ++ni) {
        int row = wx * 64 + ni * 16 + l15;
        bfr[ni][ks] = *(const short8*)&Bs[row][((ks * 4 + quad) ^ (row & 7)) * 8];
      }
    }
    #pragma unroll
    for (int ks = 0; ks < 2; ++ks)
      #pragma unroll
      for (int mi = 0; mi < 4; ++mi)
        #pragma unroll
        for (int ni = 0; ni < 4; ++ni)
          acc[mi][ni] = __builtin_amdgcn_mfma_f32_16x16x32_bf16(af[mi][ks], bfr[ni][ks], acc[mi][ni], 0, 0, 0);
  }

  // -------- register epilogue: bias + causal conv + silu, no LDS -----------
  const int d     = d0 + wx * 16 + l15;            // this lane's channel
  const float4 bv = *(const float4*)&bias[(size_t)d * 4];  // taps w=0..3
  const int tbase = m0 & (T_DIM - 1);              // tiles never straddle batch
  const int bbase = m0 - tbase;
  const float* xcol = &X[(size_t)bbase * D_DIM + d];
  float* ocol       = &Out[(size_t)m0 * D_DIM + d];

  #pragma unroll
  for (int mi = 0; mi < 4; ++mi) {
    int t0 = wy * 64 + mi * 16 + quad * 4;         // local token of r=0
    int tq = tbase + t0;                           // token within batch
    float xv[7];                                   // x[tq-3 .. tq+3] for this d
    #pragma unroll
    for (int j = 0; j < 7; ++j) {
      int tt = tq - 3 + j;
      xv[j] = (tt >= 0) ? xcol[(size_t)tt * D_DIM] : 0.f;
    }
    #pragma unroll
    for (int r = 0; r < 4; ++r) {
      float c0 = acc[mi][0][r] + bv.x;
      float c1 = acc[mi][1][r] + bv.y;
      float c2 = acc[mi][2][r] + bv.z;
      float c3 = acc[mi][3][r] + bv.w;
      float o  = c0 * xv[r] + c1 * xv[r + 1] + c2 * xv[r + 2] + c3 * xv[r + 3];
      float y  = o / (1.f + __expf(-o));
      ocol[(size_t)(t0 + r) * D_DIM] = y;
    }
  }
}

extern "C" void kernel_launch(void* const* d_in, const int* in_sizes, int n_in,
                              void* d_out, int out_size, void* d_ws, size_t ws_size,
                              hipStream_t stream) {
  const float* x  = (const float*)d_in[0];   // [4,4096,2048]
  const float* w1 = (const float*)d_in[1];   // [2048,256]
  const float* w2 = (const float*)d_in[2];   // [256,8192]
  const float* b2 = (const float*)d_in[3];   // [8192]
  float* out = (float*)d_out;                // [4,4096,2048]

  // ws layout (u16 elems): w1t 512K | w2t 2M | h 4M  (= ~13.6 MB)
  u16* w1t = (u16*)d_ws;                     // [256][2048]
  u16* w2t = w1t + (size_t)H_DIM * D_DIM;    // [8192][256]
  u16* h   = w2t + (size_t)NFLAT * H_DIM;    // [16384][256]

  tr_cvt_all<<<512 + 2048, 256, 0, stream>>>(w1, w1t, w2, w2t);
  gemm1_silu<<<dim3(4, M_DIM / 64), 256, 0, stream>>>(x, w1t, h);
  gemm2_conv_silu<<<dim3(D_DIM / 32, M_DIM / 128), 256, 0, stream>>>(h, w2t, b2, x, out);
}

// Round 6
// 341.410 us; speedup vs baseline: 1.1862x; 1.1153x over previous
//
#include <hip/hip_runtime.h>

typedef unsigned short u16;
typedef unsigned int   u32;
typedef __attribute__((ext_vector_type(8))) short short8;   // 8 bf16 (4 VGPRs)
typedef __attribute__((ext_vector_type(4))) float floatx4;  // MFMA acc

#define T_DIM 4096
#define D_DIM 2048
#define H_DIM 256
#define M_DIM 16384   // B*T
#define NFLAT 8192    // D*W

__device__ __forceinline__ u16 f2bf(float f) {
  union { float f; u32 u; } c; c.f = f;
  u32 x = c.u;
  x += 0x7FFFu + ((x >> 16) & 1u);   // RNE
  return (u16)(x >> 16);
}
__device__ __forceinline__ u32 pk2(float a, float b) {
  return (u32)f2bf(a) | ((u32)f2bf(b) << 16);
}

// async global->LDS, 16B per lane. LDS dest = wave-uniform base + lane*16.
__device__ __forceinline__ void glds16(const void* g, void* l) {
  __builtin_amdgcn_global_load_lds(
      (const __attribute__((address_space(1))) void*)g,
      (__attribute__((address_space(3))) void*)l, 16, 0, 0);
}

// ------------- fused transpose+cvt for BOTH weights (one launch) ------------
__global__ void __launch_bounds__(256) tr_cvt_all(const float* __restrict__ w1,
                                                  u16* __restrict__ w1t,
                                                  const float* __restrict__ w2,
                                                  u16* __restrict__ w2t) {
  __shared__ u16 tile[32][33];
  int bid = blockIdx.x;
  const float* src; u16* dst; int R, C, c0, r0;
  if (bid < 512) {                       // w1 [2048][256] -> w1t [256][2048]
    src = w1; dst = w1t; R = D_DIM; C = H_DIM;
    c0 = (bid & 7) * 32; r0 = (bid >> 3) * 32;
  } else {                               // w2 [256][8192] -> w2t [8192][256]
    int b = bid - 512;
    src = w2; dst = w2t; R = H_DIM; C = NFLAT;
    c0 = (b & 255) * 32; r0 = (b >> 8) * 32;
  }
  const int tx = threadIdx.x & 31;
  const int ty = threadIdx.x >> 5;       // 0..7
  #pragma unroll
  for (int i = ty; i < 32; i += 8)
    tile[i][tx] = f2bf(src[(size_t)(r0 + i) * C + (c0 + tx)]);
  __syncthreads();
  #pragma unroll
  for (int i = ty; i < 32; i += 8)
    dst[(size_t)(c0 + i) * R + (r0 + tx)] = tile[tx][i];
}

// ---------------- GEMM1: h = silu(x @ w1), fp32 x inline-cvt ----------------
// tile 32(M) x 256(N = FULL H), BK=64 -> 32 k-iters. grid = 512 blocks
// = 2 blocks/CU, 8 waves/CU. Full-H tile => X (134 MB) read exactly ONCE
// (R1-R5 split N in 2-4 tiles => 268-536 MB X traffic, the dominant cost).
// Verified 2-phase dbuf machinery, geometry only changed: As[2][32][64] 8 KB +
// Bs[2][256][64] 64 KB = 72 KB. 4 waves split N in 4 (wave 32x64, acc[2][4]).
// w1t (1 MB) is XCD-L2-resident, so per-block full re-read is L2-served.
__global__ void __launch_bounds__(256) gemm1_silu(const float* __restrict__ X,   // [M][2048]
                                                  const u16* __restrict__ Bt,    // w1t [256][2048]
                                                  u16* __restrict__ H) {         // [M][256]
  __shared__ __align__(16) u16 As[2][32][64];    //  8 KB
  __shared__ __align__(16) u16 Bs[2][256][64];   // 64 KB
  const int tid  = threadIdx.x;
  const int lane = tid & 63, l15 = lane & 15, quad = lane >> 4;
  const int wv   = tid >> 6;                     // wave = N quadrant (64 cols)
  const int m0   = blockIdx.x * 32;
  const int srow = lane >> 3, sc = lane & 7;     // glds chunk coords

  floatx4 acc[2][4];
  const floatx4 zf = {0.f, 0.f, 0.f, 0.f};
  #pragma unroll
  for (int i = 0; i < 2; ++i)
    #pragma unroll
    for (int j = 0; j < 4; ++j) acc[i][j] = zf;

  float4 fA[2];                                  // A fp32 reg prefetch (one tile)

#define G1_LOADA(KT)                                                          \
  {                                                                           \
    int row = tid >> 3, g = tid & 7;                                          \
    const float* xs = &X[(size_t)(m0 + row) * D_DIM + (KT) * 64 + g * 8];     \
    fA[0] = *(const float4*)xs;                                               \
    fA[1] = *(const float4*)(xs + 4);                                         \
  }

#define G1_WRITEA(BUF)                                                        \
  {                                                                           \
    int row = tid >> 3, g = tid & 7, c = g ^ (row & 7);                       \
    uint4 pk;                                                                 \
    pk.x = pk2(fA[0].x, fA[0].y);                                             \
    pk.y = pk2(fA[0].z, fA[0].w);                                             \
    pk.z = pk2(fA[1].x, fA[1].y);                                             \
    pk.w = pk2(fA[1].z, fA[1].w);                                             \
    *(uint4*)&As[BUF][row][c * 8] = pk;                                       \
  }

#define G1_STAGEB(KT, BUF)                                                    \
  _Pragma("unroll")                                                           \
  for (int ci = 0; ci < 8; ++ci) {               /* 32 chunks, 8 per wave */  \
    int ch  = wv * 8 + ci;                                                    \
    int row = ch * 8 + srow;                     /* 0..255 = full H */        \
    glds16(&Bt[(size_t)row * D_DIM + (KT) * 64 + (sc ^ (row & 7)) * 8],       \
           (char*)Bs + (BUF) * 32768 + ch * 1024);                            \
  }

  // prologue: tile 0 resident, fA holds tile 1
  G1_LOADA(0);
  G1_STAGEB(0, 0);
  G1_WRITEA(0);          // waits fA(0)
  G1_LOADA(1);
  __syncthreads();       // drain glds(0) + fA(1)

  #pragma unroll 2
  for (int t = 0; t < 32; ++t) {
    const int b = t & 1;
    if (t + 1 < 32) {
      G1_WRITEA(b ^ 1);          // tile t+1 from fA (loaded iter t-1: no stall)
      G1_STAGEB(t + 1, b ^ 1);
    }
    if (t + 2 < 32) G1_LOADA(t + 2);
    short8 af[2][2], bfr[4][2];
    #pragma unroll
    for (int ks = 0; ks < 2; ++ks) {
      #pragma unroll
      for (int mi = 0; mi < 2; ++mi) {
        int row = mi * 16 + l15;
        af[mi][ks] = *(const short8*)&As[b][row][((ks * 4 + quad) ^ (row & 7)) * 8];
      }
      #pragma unroll
      for (int ni = 0; ni < 4; ++ni) {
        int row = wv * 64 + ni * 16 + l15;
        bfr[ni][ks] = *(const short8*)&Bs[b][row][((ks * 4 + quad) ^ (row & 7)) * 8];
      }
    }
    #pragma unroll
    for (int ks = 0; ks < 2; ++ks)
      #pragma unroll
      for (int mi = 0; mi < 2; ++mi)
        #pragma unroll
        for (int ni = 0; ni < 4; ++ni)
          acc[mi][ni] = __builtin_amdgcn_mfma_f32_16x16x32_bf16(af[mi][ks], bfr[ni][ks], acc[mi][ni], 0, 0, 0);
    if (t + 1 < 32) __syncthreads();   // ONE drain/barrier per iter; none after last
  }

  #pragma unroll
  for (int mi = 0; mi < 2; ++mi)
    #pragma unroll
    for (int ni = 0; ni < 4; ++ni)
      #pragma unroll
      for (int r = 0; r < 4; ++r) {
        float v = acc[mi][ni][r];
        v = v / (1.f + __expf(-v));
        int row = m0 + mi * 16 + quad * 4 + r;
        int col = wv * 64 + ni * 16 + l15;
        H[(size_t)row * H_DIM + col] = f2bf(v);
      }
#undef G1_LOADA
#undef G1_WRITEA
#undef G1_STAGEB
}

// ---- GEMM2 fused: flat = h @ w2 + b2 ; out = silu(conv(flat, x)) ----------
// EXACT Round-1 kernel (measured 100 us; every restructure since regressed,
// including the R5 XCD swizzle: FETCH 100->307 MB because the DEFAULT mapping
// already pins XCD = bx%8 -> stable 512 KB w2t slice per XCD-L2).
// tile 128 tokens x 128 flat cols, BK=64, 4 iters, single-buffer 32 KB,
// {sync; stage; sync; compute} per iter, permuted-B register conv epilogue.
__global__ void __launch_bounds__(256) gemm2_conv_silu(const u16* __restrict__ Hin,   // [M][256] bf16
                                                       const u16* __restrict__ Bt,    // w2t [8192][256] bf16
                                                       const float* __restrict__ bias,// [8192] fp32
                                                       const float* __restrict__ X,   // [M][2048] fp32
                                                       float* __restrict__ Out) {     // [M][2048] fp32
  __shared__ __align__(16) u16 As[128][64];   // 16 KB
  __shared__ __align__(16) u16 Bs[128][64];   // 16 KB
  const int tid  = threadIdx.x;
  const int lane = tid & 63, l15 = lane & 15, quad = lane >> 4;
  const int wv   = tid >> 6, wy = wv >> 1, wx = wv & 1;
  const int m0   = blockIdx.y * 128;
  const int d0   = blockIdx.x * 32;
  const int srow = lane >> 3, sc = lane & 7;

  floatx4 acc[4][4];
  const floatx4 zf = {0.f, 0.f, 0.f, 0.f};
  #pragma unroll
  for (int i = 0; i < 4; ++i)
    #pragma unroll
    for (int j = 0; j < 4; ++j) acc[i][j] = zf;

  for (int k0 = 0; k0 < H_DIM; k0 += 64) {    // 4 iterations
    __syncthreads();
    #pragma unroll
    for (int ci = 0; ci < 4; ++ci) {
      int ch  = ci * 4 + wv;                  // 16 chunks of 1 KB each
      int row = ch * 8 + srow;                // 0..127
      int g   = (sc ^ (row & 7)) * 8;         // swizzled k-chunk source
      glds16(&Hin[(size_t)(m0 + row) * H_DIM + k0 + g], (char*)As + ch * 1024);
      // permuted w2t row: Bs row (wx*64+ni*16+l15) <-> flat col (d0+wx*16+l15)*4+ni
      int fc = (d0 + ((row >> 6) << 4) + (row & 15)) * 4 + ((row >> 4) & 3);
      glds16(&Bt[(size_t)fc * H_DIM + k0 + g], (char*)Bs + ch * 1024);
    }
    __syncthreads();
    short8 af[4][2], bfr[4][2];
    #pragma unroll
    for (int ks = 0; ks < 2; ++ks) {
      #pragma unroll
      for (int mi = 0; mi < 4; ++mi) {
        int row = wy * 64 + mi * 16 + l15;
        af[mi][ks] = *(const short8*)&As[row][((ks * 4 + quad) ^ (row & 7)) * 8];
      }
      #pragma unroll
      for (int ni = 0; ni < 4; ++ni) {
        int row = wx * 64 + ni * 16 + l15;
        bfr[ni][ks] = *(const short8*)&Bs[row][((ks * 4 + quad) ^ (row & 7)) * 8];
      }
    }
    #pragma unroll
    for (int ks = 0; ks < 2; ++ks)
      #pragma unroll
      for (int mi = 0; mi < 4; ++mi)
        #pragma unroll
        for (int ni = 0; ni < 4; ++ni)
          acc[mi][ni] = __builtin_amdgcn_mfma_f32_16x16x32_bf16(af[mi][ks], bfr[ni][ks], acc[mi][ni], 0, 0, 0);
  }

  // -------- register epilogue: bias + causal conv + silu, no LDS -----------
  const int d     = d0 + wx * 16 + l15;            // this lane's channel
  const float4 bv = *(const float4*)&bias[(size_t)d * 4];  // taps w=0..3
  const int tbase = m0 & (T_DIM - 1);              // tiles never straddle batch
  const int bbase = m0 - tbase;
  const float* xcol = &X[(size_t)bbase * D_DIM + d];
  float* ocol       = &Out[(size_t)m0 * D_DIM + d];

  #pragma unroll
  for (int mi = 0; mi < 4; ++mi) {
    int t0 = wy * 64 + mi * 16 + quad * 4;         // local token of r=0
    int tq = tbase + t0;                           // token within batch
    float xv[7];                                   // x[tq-3 .. tq+3] for this d
    #pragma unroll
    for (int j = 0; j < 7; ++j) {
      int tt = tq - 3 + j;
      xv[j] = (tt >= 0) ? xcol[(size_t)tt * D_DIM] : 0.f;
    }
    #pragma unroll
    for (int r = 0; r < 4; ++r) {
      float c0 = acc[mi][0][r] + bv.x;
      float c1 = acc[mi][1][r] + bv.y;
      float c2 = acc[mi][2][r] + bv.z;
      float c3 = acc[mi][3][r] + bv.w;
      float o  = c0 * xv[r] + c1 * xv[r + 1] + c2 * xv[r + 2] + c3 * xv[r + 3];
      float y  = o / (1.f + __expf(-o));
      ocol[(size_t)(t0 + r) * D_DIM] = y;
    }
  }
}

extern "C" void kernel_launch(void* const* d_in, const int* in_sizes, int n_in,
                              void* d_out, int out_size, void* d_ws, size_t ws_size,
                              hipStream_t stream) {
  const float* x  = (const float*)d_in[0];   // [4,4096,2048]
  const float* w1 = (const float*)d_in[1];   // [2048,256]
  const float* w2 = (const float*)d_in[2];   // [256,8192]
  const float* b2 = (const float*)d_in[3];   // [8192]
  float* out = (float*)d_out;                // [4,4096,2048]

  // ws layout (u16 elems): w1t 512K | w2t 2M | h 4M  (= ~13.6 MB)
  u16* w1t = (u16*)d_ws;                     // [256][2048]
  u16* w2t = w1t + (size_t)H_DIM * D_DIM;    // [8192][256]
  u16* h   = w2t + (size_t)NFLAT * H_DIM;    // [16384][256]

  tr_cvt_all<<<512 + 2048, 256, 0, stream>>>(w1, w1t, w2, w2t);
  gemm1_silu<<<M_DIM / 32, 256, 0, stream>>>(x, w1t, h);
  gemm2_conv_silu<<<dim3(D_DIM / 32, M_DIM / 128), 256, 0, stream>>>(h, w2t, b2, x, out);
}

// Round 7
// 330.242 us; speedup vs baseline: 1.2263x; 1.0338x over previous
//
#include <hip/hip_runtime.h>

typedef unsigned short u16;
typedef unsigned int   u32;
typedef __attribute__((ext_vector_type(8))) short short8;   // 8 bf16 (4 VGPRs)
typedef __attribute__((ext_vector_type(4))) float floatx4;  // MFMA acc

#define T_DIM 4096
#define D_DIM 2048
#define H_DIM 256
#define M_DIM 16384   // B*T
#define NFLAT 8192    // D*W

__device__ __forceinline__ u16 f2bf(float f) {
  union { float f; u32 u; } c; c.f = f;
  u32 x = c.u;
  x += 0x7FFFu + ((x >> 16) & 1u);   // RNE
  return (u16)(x >> 16);
}
__device__ __forceinline__ u32 pk2(float a, float b) {
  return (u32)f2bf(a) | ((u32)f2bf(b) << 16);
}

// async global->LDS, 16B per lane. LDS dest = wave-uniform base + lane*16.
__device__ __forceinline__ void glds16(const void* g, void* l) {
  __builtin_amdgcn_global_load_lds(
      (const __attribute__((address_space(1))) void*)g,
      (__attribute__((address_space(3))) void*)l, 16, 0, 0);
}

// ------------- fused transpose+cvt for BOTH weights (one launch) ------------
__global__ void __launch_bounds__(256) tr_cvt_all(const float* __restrict__ w1,
                                                  u16* __restrict__ w1t,
                                                  const float* __restrict__ w2,
                                                  u16* __restrict__ w2t) {
  __shared__ u16 tile[32][33];
  int bid = blockIdx.x;
  const float* src; u16* dst; int R, C, c0, r0;
  if (bid < 512) {                       // w1 [2048][256] -> w1t [256][2048]
    src = w1; dst = w1t; R = D_DIM; C = H_DIM;
    c0 = (bid & 7) * 32; r0 = (bid >> 3) * 32;
  } else {                               // w2 [256][8192] -> w2t [8192][256]
    int b = bid - 512;
    src = w2; dst = w2t; R = H_DIM; C = NFLAT;
    c0 = (b & 255) * 32; r0 = (b >> 8) * 32;
  }
  const int tx = threadIdx.x & 31;
  const int ty = threadIdx.x >> 5;       // 0..7
  #pragma unroll
  for (int i = ty; i < 32; i += 8)
    tile[i][tx] = f2bf(src[(size_t)(r0 + i) * C + (c0 + tx)]);
  __syncthreads();
  #pragma unroll
  for (int i = ty; i < 32; i += 8)
    dst[(size_t)(c0 + i) * R + (r0 + tx)] = tile[tx][i];
}

// ---------------- GEMM1: h = silu(x @ w1), fp32 x inline-cvt ----------------
// tile 32(M) x 256(N = FULL H), BK=64 -> 32 k-iters, 512 blocks (X read ONCE).
// COUNTED-VMCNT 2-phase (m201-style): raw s_barrier + s_waitcnt vmcnt(2) in
// steady state (never 0) so glds(t+1) spans the compute phase and the fA HBM
// prefetch (depth-2: issued at t, consumed at t+2) is NEVER drained at a
// barrier. R1-R6 used __syncthreads whose mandatory vmcnt(0) serialized a
// ~900cy HBM latency into every one of the 32 iterations (gemm1 was invariant
// at ~90us across tilings -- structure-bound, not BW-bound).
__global__ void __launch_bounds__(256) gemm1_silu(const float* __restrict__ X,   // [M][2048]
                                                  const u16* __restrict__ Bt,    // w1t [256][2048]
                                                  u16* __restrict__ H) {         // [M][256]
  __shared__ __align__(16) u16 As[2][32][64];    //  8 KB
  __shared__ __align__(16) u16 Bs[2][256][64];   // 64 KB
  const int tid  = threadIdx.x;
  const int lane = tid & 63, l15 = lane & 15, quad = lane >> 4;
  const int wv   = tid >> 6;                     // wave = N quadrant (64 cols)
  const int m0   = blockIdx.x * 32;
  const int srow = lane >> 3, sc = lane & 7;     // glds chunk coords

  floatx4 acc[2][4];
  const floatx4 zf = {0.f, 0.f, 0.f, 0.f};
  #pragma unroll
  for (int i = 0; i < 2; ++i)
    #pragma unroll
    for (int j = 0; j < 4; ++j) acc[i][j] = zf;

  float4 fA0[2], fA1[2];   // A fp32 prefetch regs; A(k) lives in slot k&1

#define G1_LOADA(KT, FW)                                                      \
  {                                                                           \
    int row = tid >> 3, g = tid & 7;                                          \
    const float* xs = &X[(size_t)(m0 + row) * D_DIM + (KT) * 64 + g * 8];     \
    FW[0] = *(const float4*)xs;                                               \
    FW[1] = *(const float4*)(xs + 4);                                         \
  }

#define G1_WRITEA(BUF, FW)                                                    \
  {                                                                           \
    int row = tid >> 3, g = tid & 7, c = g ^ (row & 7);                       \
    uint4 pk;                                                                 \
    pk.x = pk2(FW[0].x, FW[0].y);                                             \
    pk.y = pk2(FW[0].z, FW[0].w);                                             \
    pk.z = pk2(FW[1].x, FW[1].y);                                             \
    pk.w = pk2(FW[1].z, FW[1].w);                                             \
    *(uint4*)&As[BUF][row][c * 8] = pk;                                       \
  }

#define G1_STAGEB(KT, BUF)                                                    \
  _Pragma("unroll")                                                           \
  for (int ci = 0; ci < 8; ++ci) {               /* 32 chunks, 8 per wave */  \
    int ch  = wv * 8 + ci;                                                    \
    int row = ch * 8 + srow;                     /* 0..255 = full H */        \
    glds16(&Bt[(size_t)row * D_DIM + (KT) * 64 + (sc ^ (row & 7)) * 8],       \
           (char*)Bs + (BUF) * 32768 + ch * 1024);                            \
  }

// stage phase of iter T: write A(T+1) (regs loaded at T-2: complete), issue
// glds B(T+1), then issue fA(T+3). sched_barrier(0) pins glds BEFORE fA so
// the end-of-iter vmcnt(2) count is exact.
#define G1_STAGE_NEXT(T, BUFN, FW)                                            \
  if ((T) + 1 < 32) {                                                         \
    G1_WRITEA(BUFN, FW);                                                      \
    __builtin_amdgcn_sched_barrier(0);                                        \
    G1_STAGEB((T) + 1, BUFN);                                                 \
    __builtin_amdgcn_sched_barrier(0);                                        \
    if ((T) + 3 < 32) { G1_LOADA((T) + 3, FW); }                              \
  }

#define G1_COMPUTE(BUFC)                                                      \
  {                                                                           \
    short8 af[2][2], bfr[4][2];                                               \
    _Pragma("unroll")                                                         \
    for (int ks = 0; ks < 2; ++ks) {                                          \
      _Pragma("unroll")                                                       \
      for (int mi = 0; mi < 2; ++mi) {                                        \
        int row = mi * 16 + l15;                                              \
        af[mi][ks] = *(const short8*)&As[BUFC][row][((ks * 4 + quad) ^ (row & 7)) * 8]; \
      }                                                                       \
      _Pragma("unroll")                                                       \
      for (int ni = 0; ni < 4; ++ni) {                                        \
        int row = wv * 64 + ni * 16 + l15;                                    \
        bfr[ni][ks] = *(const short8*)&Bs[BUFC][row][((ks * 4 + quad) ^ (row & 7)) * 8]; \
      }                                                                       \
    }                                                                         \
    _Pragma("unroll")                                                         \
    for (int ks = 0; ks < 2; ++ks)                                            \
      _Pragma("unroll")                                                       \
      for (int mi = 0; mi < 2; ++mi)                                          \
        _Pragma("unroll")                                                     \
        for (int ni = 0; ni < 4; ++ni)                                        \
          acc[mi][ni] = __builtin_amdgcn_mfma_f32_16x16x32_bf16(af[mi][ks], bfr[ni][ks], acc[mi][ni], 0, 0, 0); \
  }

// end-of-iter publish: wait COUNTED vmcnt (leave fA(T+3) in flight when it
// exists), drain own LDS ops, raw barrier. Never vmcnt(0) until the tail.
#define G1_SYNC(T)                                                            \
  if ((T) + 1 < 32) {                                                         \
    if ((T) <= 28) { asm volatile("s_waitcnt vmcnt(2)" ::: "memory"); }       \
    else           { asm volatile("s_waitcnt vmcnt(0)" ::: "memory"); }       \
    asm volatile("s_waitcnt lgkmcnt(0)" ::: "memory");                        \
    __builtin_amdgcn_sched_barrier(0);                                        \
    __builtin_amdgcn_s_barrier();                                             \
    __builtin_amdgcn_sched_barrier(0);                                        \
  }

  // prologue: A(0),A(1) loads; write A(0); glds B(0); issue A(2); publish buf0
  G1_LOADA(0, fA0);
  G1_LOADA(1, fA1);
  G1_WRITEA(0, fA0);                 // auto-waits fA0 only (2 newer loads)
  __builtin_amdgcn_sched_barrier(0);
  G1_STAGEB(0, 0);
  __builtin_amdgcn_sched_barrier(0);
  G1_LOADA(2, fA0);
  asm volatile("s_waitcnt vmcnt(2)" ::: "memory");   // glds(0)+fA1 done; fA2 in flight
  asm volatile("s_waitcnt lgkmcnt(0)" ::: "memory"); // ds_write A(0) done
  __builtin_amdgcn_sched_barrier(0);
  __builtin_amdgcn_s_barrier();
  __builtin_amdgcn_sched_barrier(0);

  for (int tt = 0; tt < 32; tt += 2) {
    // even iter: compute buf0, stage into buf1, A-slot 1
    G1_STAGE_NEXT(tt, 1, fA1);
    G1_COMPUTE(0);
    G1_SYNC(tt);
    // odd iter: compute buf1, stage into buf0, A-slot 0
    G1_STAGE_NEXT(tt + 1, 0, fA0);
    G1_COMPUTE(1);
    G1_SYNC(tt + 1);
  }

  #pragma unroll
  for (int mi = 0; mi < 2; ++mi)
    #pragma unroll
    for (int ni = 0; ni < 4; ++ni)
      #pragma unroll
      for (int r = 0; r < 4; ++r) {
        float v = acc[mi][ni][r];
        v = v / (1.f + __expf(-v));
        int row = m0 + mi * 16 + quad * 4 + r;
        int col = wv * 64 + ni * 16 + l15;
        H[(size_t)row * H_DIM + col] = f2bf(v);
      }
#undef G1_LOADA
#undef G1_WRITEA
#undef G1_STAGEB
#undef G1_STAGE_NEXT
#undef G1_COMPUTE
#undef G1_SYNC
}

// ---- GEMM2 fused: flat = h @ w2 + b2 ; out = silu(conv(flat, x)) ----------
// EXACT Round-1 kernel (verified twice at ~101 us; every restructure
// regressed). tile 128 tokens x 128 flat cols, BK=64, 4 iters, single-buffer
// 32 KB, {sync; stage; sync; compute} per iter, permuted-B register conv
// epilogue. Default block->XCD mapping (bx%8) keeps w2t slices L2-pinned.
__global__ void __launch_bounds__(256) gemm2_conv_silu(const u16* __restrict__ Hin,   // [M][256] bf16
                                                       const u16* __restrict__ Bt,    // w2t [8192][256] bf16
                                                       const float* __restrict__ bias,// [8192] fp32
                                                       const float* __restrict__ X,   // [M][2048] fp32
                                                       float* __restrict__ Out) {     // [M][2048] fp32
  __shared__ __align__(16) u16 As[128][64];   // 16 KB
  __shared__ __align__(16) u16 Bs[128][64];   // 16 KB
  const int tid  = threadIdx.x;
  const int lane = tid & 63, l15 = lane & 15, quad = lane >> 4;
  const int wv   = tid >> 6, wy = wv >> 1, wx = wv & 1;
  const int m0   = blockIdx.y * 128;
  const int d0   = blockIdx.x * 32;
  const int srow = lane >> 3, sc = lane & 7;

  floatx4 acc[4][4];
  const floatx4 zf = {0.f, 0.f, 0.f, 0.f};
  #pragma unroll
  for (int i = 0; i < 4; ++i)
    #pragma unroll
    for (int j = 0; j < 4; ++j) acc[i][j] = zf;

  for (int k0 = 0; k0 < H_DIM; k0 += 64) {    // 4 iterations
    __syncthreads();
    #pragma unroll
    for (int ci = 0; ci < 4; ++ci) {
      int ch  = ci * 4 + wv;                  // 16 chunks of 1 KB each
      int row = ch * 8 + srow;                // 0..127
      int g   = (sc ^ (row & 7)) * 8;         // swizzled k-chunk source
      glds16(&Hin[(size_t)(m0 + row) * H_DIM + k0 + g], (char*)As + ch * 1024);
      // permuted w2t row: Bs row (wx*64+ni*16+l15) <-> flat col (d0+wx*16+l15)*4+ni
      int fc = (d0 + ((row >> 6) << 4) + (row & 15)) * 4 + ((row >> 4) & 3);
      glds16(&Bt[(size_t)fc * H_DIM + k0 + g], (char*)Bs + ch * 1024);
    }
    __syncthreads();
    short8 af[4][2], bfr[4][2];
    #pragma unroll
    for (int ks = 0; ks < 2; ++ks) {
      #pragma unroll
      for (int mi = 0; mi < 4; ++mi) {
        int row = wy * 64 + mi * 16 + l15;
        af[mi][ks] = *(const short8*)&As[row][((ks * 4 + quad) ^ (row & 7)) * 8];
      }
      #pragma unroll
      for (int ni = 0; ni < 4; ++ni) {
        int row = wx * 64 + ni * 16 + l15;
        bfr[ni][ks] = *(const short8*)&Bs[row][((ks * 4 + quad) ^ (row & 7)) * 8];
      }
    }
    #pragma unroll
    for (int ks = 0; ks < 2; ++ks)
      #pragma unroll
      for (int mi = 0; mi < 4; ++mi)
        #pragma unroll
        for (int ni = 0; ni < 4; ++ni)
          acc[mi][ni] = __builtin_amdgcn_mfma_f32_16x16x32_bf16(af[mi][ks], bfr[ni][ks], acc[mi][ni], 0, 0, 0);
  }

  // -------- register epilogue: bias + causal conv + silu, no LDS -----------
  const int d     = d0 + wx * 16 + l15;            // this lane's channel
  const float4 bv = *(const float4*)&bias[(size_t)d * 4];  // taps w=0..3
  const int tbase = m0 & (T_DIM - 1);              // tiles never straddle batch
  const int bbase = m0 - tbase;
  const float* xcol = &X[(size_t)bbase * D_DIM + d];
  float* ocol       = &Out[(size_t)m0 * D_DIM + d];

  #pragma unroll
  for (int mi = 0; mi < 4; ++mi) {
    int t0 = wy * 64 + mi * 16 + quad * 4;         // local token of r=0
    int tq = tbase + t0;                           // token within batch
    float xv[7];                                   // x[tq-3 .. tq+3] for this d
    #pragma unroll
    for (int j = 0; j < 7; ++j) {
      int tt = tq - 3 + j;
      xv[j] = (tt >= 0) ? xcol[(size_t)tt * D_DIM] : 0.f;
    }
    #pragma unroll
    for (int r = 0; r < 4; ++r) {
      float c0 = acc[mi][0][r] + bv.x;
      float c1 = acc[mi][1][r] + bv.y;
      float c2 = acc[mi][2][r] + bv.z;
      float c3 = acc[mi][3][r] + bv.w;
      float o  = c0 * xv[r] + c1 * xv[r + 1] + c2 * xv[r + 2] + c3 * xv[r + 3];
      float y  = o / (1.f + __expf(-o));
      ocol[(size_t)(t0 + r) * D_DIM] = y;
    }
  }
}

extern "C" void kernel_launch(void* const* d_in, const int* in_sizes, int n_in,
                              void* d_out, int out_size, void* d_ws, size_t ws_size,
                              hipStream_t stream) {
  const float* x  = (const float*)d_in[0];   // [4,4096,2048]
  const float* w1 = (const float*)d_in[1];   // [2048,256]
  const float* w2 = (const float*)d_in[2];   // [256,8192]
  const float* b2 = (const float*)d_in[3];   // [8192]
  float* out = (float*)d_out;                // [4,4096,2048]

  // ws layout (u16 elems): w1t 512K | w2t 2M | h 4M  (= ~13.6 MB)
  u16* w1t = (u16*)d_ws;                     // [256][2048]
  u16* w2t = w1t + (size_t)H_DIM * D_DIM;    // [8192][256]
  u16* h   = w2t + (size_t)NFLAT * H_DIM;    // [16384][256]

  tr_cvt_all<<<512 + 2048, 256, 0, stream>>>(w1, w1t, w2, w2t);
  gemm1_silu<<<M_DIM / 32, 256, 0, stream>>>(x, w1t, h);
  gemm2_conv_silu<<<dim3(D_DIM / 32, M_DIM / 128), 256, 0, stream>>>(h, w2t, b2, x, out);
}